// Round 6
// baseline (1875.900 us; speedup 1.0000x reference)
//
#include <hip/hip_runtime.h>
#include <math.h>

#define N_TOT 32768
#define K_CB 8192
#define D_DIM 256

#define OUT_IDX  (N_TOT * D_DIM)   // 8388608
#define OUT_LOSS (OUT_IDX + N_TOT) // 8421376
#define OUT_PERP (OUT_LOSS + 1)

// ---- workspace layout (bytes), total 50,405,376 (proven budget) ----
#define WS_AIMG   0u
#define AIMG_SZ   (256u * 16u * 8192u)           // 33,554,432
#define WS_BIMG   (WS_AIMG + AIMG_SZ)
#define BIMG_SZ   (64u * 16u * 8192u)            // 8,388,608
#define WS_PART   (WS_BIMG + BIMG_SZ)            // 16 slices x 32768 x float4
#define PART_SZ   (16u * 32768u * 16u)           // 8,388,608
#define WS_ESQ    (WS_PART + PART_SZ)            // 8192 f32
#define WS_COUNTS (WS_ESQ + 32768u)              // 8192 f32
#define WS_LPART  (WS_COUNTS + 32768u)           // 2048 f32 loss partials

typedef short bf16x8 __attribute__((ext_vector_type(8)));
typedef float f32x4  __attribute__((ext_vector_type(4)));
typedef unsigned short u16x8 __attribute__((ext_vector_type(8)));

__device__ __forceinline__ unsigned short f2bf(float x) {  // RNE f32 -> bf16
  unsigned int b = __float_as_uint(x);
  b = b + 0x7FFFu + ((b >> 16) & 1u);
  return (unsigned short)(b >> 16);
}
__device__ __forceinline__ float bf2f(unsigned short h) {
  return __uint_as_float(((unsigned int)h) << 16);
}
__device__ __forceinline__ void gld16(const void* g, void* l) {
  __builtin_amdgcn_global_load_lds(
      (const __attribute__((address_space(1))) void*)g,
      (__attribute__((address_space(3))) void*)l, 16, 0, 0);
}

// ---------------- prep: Z -> packed swizzled bf16 hi/lo tile image ----------------
// Chunk c of row r stored at slot c ^ ((r>>1)&3): linear global_load_lds lands it
// pre-swizzled; the frag ds_read applies the same XOR (both-sides rule).
__global__ __launch_bounds__(256) void prep_z(const float* __restrict__ Z,
                                              char* __restrict__ Aimg) {
  const int tid = threadIdx.x;
  const int row = blockIdx.x * 8 + (tid >> 5);
  const int ch = tid & 31;           // kt = ch>>2, chunk c = ch&3
  const int kt = ch >> 2, c = ch & 3;
  const int rb = row >> 7, r = row & 127;
  const float4 z0 = *(const float4*)(Z + (size_t)row * D_DIM + kt * 32 + c * 8);
  const float4 z1 = *(const float4*)(Z + (size_t)row * D_DIM + kt * 32 + c * 8 + 4);
  u16x8 h, l;
  h[0] = f2bf(z0.x); l[0] = f2bf(z0.x - bf2f(h[0]));
  h[1] = f2bf(z0.y); l[1] = f2bf(z0.y - bf2f(h[1]));
  h[2] = f2bf(z0.z); l[2] = f2bf(z0.z - bf2f(h[2]));
  h[3] = f2bf(z0.w); l[3] = f2bf(z0.w - bf2f(h[3]));
  h[4] = f2bf(z1.x); l[4] = f2bf(z1.x - bf2f(h[4]));
  h[5] = f2bf(z1.y); l[5] = f2bf(z1.y - bf2f(h[5]));
  h[6] = f2bf(z1.z); l[6] = f2bf(z1.z - bf2f(h[6]));
  h[7] = f2bf(z1.w); l[7] = f2bf(z1.w - bf2f(h[7]));
  const int cs = c ^ ((r >> 1) & 3);
  const size_t off = (size_t)r * 64 + cs * 16;
  *(u16x8*)(Aimg + (size_t)(rb * 16 + kt) * 8192 + off) = h;
  *(u16x8*)(Aimg + (size_t)(rb * 16 + 8 + kt) * 8192 + off) = l;
}

// ---------------- prep: E -> packed swizzled image + e_sq ----------------
__global__ __launch_bounds__(256) void prep_e(const float* __restrict__ E,
                                              char* __restrict__ Bimg,
                                              float* __restrict__ esqg) {
  const int tid = threadIdx.x;
  const int code = blockIdx.x * 8 + (tid >> 5);
  const int ch = tid & 31;
  const int kt = ch >> 2, c = ch & 3;
  const int ntg = code >> 7, r = code & 127;
  const float4 e0 = *(const float4*)(E + (size_t)code * D_DIM + kt * 32 + c * 8);
  const float4 e1 = *(const float4*)(E + (size_t)code * D_DIM + kt * 32 + c * 8 + 4);
  u16x8 h, l;
  h[0] = f2bf(e0.x); l[0] = f2bf(e0.x - bf2f(h[0]));
  h[1] = f2bf(e0.y); l[1] = f2bf(e0.y - bf2f(h[1]));
  h[2] = f2bf(e0.z); l[2] = f2bf(e0.z - bf2f(h[2]));
  h[3] = f2bf(e0.w); l[3] = f2bf(e0.w - bf2f(h[3]));
  h[4] = f2bf(e1.x); l[4] = f2bf(e1.x - bf2f(h[4]));
  h[5] = f2bf(e1.y); l[5] = f2bf(e1.y - bf2f(h[5]));
  h[6] = f2bf(e1.z); l[6] = f2bf(e1.z - bf2f(h[6]));
  h[7] = f2bf(e1.w); l[7] = f2bf(e1.w - bf2f(h[7]));
  const int cs = c ^ ((r >> 1) & 3);
  const size_t off = (size_t)r * 64 + cs * 16;
  *(u16x8*)(Bimg + (size_t)(ntg * 16 + kt) * 8192 + off) = h;
  *(u16x8*)(Bimg + (size_t)(ntg * 16 + 8 + kt) * 8192 + off) = l;
  float s = e0.x * e0.x + e0.y * e0.y + e0.z * e0.z + e0.w * e0.w +
            e1.x * e1.x + e1.y * e1.y + e1.z * e1.z + e1.w * e1.w;
#pragma unroll
  for (int o = 16; o > 0; o >>= 1) s += __shfl_down(s, o, 32);
  if ((tid & 31) == 0) esqg[code] = s;
}

// ---------------- MFMA distance GEMM + fused top-2 argmin ----------------
// 256 rows x 512 codes per block (2 code-tiles of 256), 8 waves (2x4),
// per-wave 128x64. 16 chunks (2 tiles x 8 K-steps); per chunk stage
// {Ah,Al,Bh,Bl} 64 KB double-buffered with COUNTED vmcnt(8) + raw barriers
// (loads stay in flight across barriers), 3 products (zh*eh + zh*el + zl*eh).
__global__ __launch_bounds__(512, 2) void argmin_mfma(
    const char* __restrict__ Aimg, const char* __restrict__ Bimg,
    const float* __restrict__ esqg, float4* __restrict__ partials) {
  __shared__ __align__(16) struct { char Ah[16384]; char Al[16384];
                                    char Bh[16384]; char Bl[16384]; } lds[2];  // 128 KB
  __shared__ __align__(16) float4 mrg[256][4];                                 // 16 KB
  __shared__ float esq_s[512];                                                 // 2 KB

  const int tid = threadIdx.x;
  const int lane = tid & 63;
  const int wid = tid >> 6;
  const int wrow = wid >> 2, wcol = wid & 3;
  const int lrow = lane & 15, lgrp = lane >> 4;
  const int rb = blockIdx.x >> 4;   // 0..127 (256 rows each)
  const int ct = blockIdx.x & 15;   // 0..15 (512 codes each); XCD = ct&7
  const int rb2 = rb * 2;
  const int so = tid * 16;

  // frag read: within-tile row R's chunk lgrp lives at slot lgrp ^ ((R>>1)&3);
  // R = 16*rf + lrow (A) / 64*(wcol&1)+16*cf+lrow (B) -> XOR depends only on lrow.
  const int sw = (lrow >> 1) & 3;
  const int slot = (lgrp ^ sw) * 16;
  const int abase = wrow * 8192 + lrow * 64 + slot;                       // + rf*1024
  const int bbase = (wcol >> 1) * 8192 + ((wcol & 1) * 64 + lrow) * 64 + slot;  // + cf*1024

#define STAGE_K(cn, BI) do {                                                   \
    const int k_ = (cn) & 7, t_ = (cn) >> 3;                                   \
    const int ga_ = rb2 * 16 + k_, gb_ = (rb2 + 1) * 16 + k_;                  \
    const int g0_ = (ct * 4 + t_ * 2) * 16 + k_, g1_ = g0_ + 16;               \
    gld16(Aimg + (size_t)ga_ * 8192 + so,       lds[BI].Ah + so);              \
    gld16(Aimg + (size_t)gb_ * 8192 + so,       lds[BI].Ah + 8192 + so);       \
    gld16(Aimg + (size_t)(ga_ + 8) * 8192 + so, lds[BI].Al + so);              \
    gld16(Aimg + (size_t)(gb_ + 8) * 8192 + so, lds[BI].Al + 8192 + so);       \
    gld16(Bimg + (size_t)g0_ * 8192 + so,       lds[BI].Bh + so);              \
    gld16(Bimg + (size_t)g1_ * 8192 + so,       lds[BI].Bh + 8192 + so);       \
    gld16(Bimg + (size_t)(g0_ + 8) * 8192 + so, lds[BI].Bl + so);              \
    gld16(Bimg + (size_t)(g1_ + 8) * 8192 + so, lds[BI].Bl + 8192 + so);       \
  } while (0)

#define COMPUTE_K(BI) do {                                                     \
    bf16x8 fa[8], fb[4], fc[4];                                                \
    _Pragma("unroll")                                                          \
    for (int rf = 0; rf < 8; rf++)                                             \
      fa[rf] = *(const bf16x8*)(lds[BI].Ah + abase + rf * 1024);               \
    _Pragma("unroll")                                                          \
    for (int cf = 0; cf < 4; cf++)                                             \
      fb[cf] = *(const bf16x8*)(lds[BI].Bh + bbase + cf * 1024);               \
    __builtin_amdgcn_s_setprio(1);                                             \
    _Pragma("unroll")                                                          \
    for (int rf = 0; rf < 8; rf++)                                             \
      _Pragma("unroll")                                                        \
      for (int cf = 0; cf < 4; cf++)                                           \
        acc[rf][cf] = __builtin_amdgcn_mfma_f32_16x16x32_bf16(fa[rf], fb[cf], acc[rf][cf], 0, 0, 0); \
    __builtin_amdgcn_s_setprio(0);                                             \
    _Pragma("unroll")                                                          \
    for (int cf = 0; cf < 4; cf++)                                             \
      fc[cf] = *(const bf16x8*)(lds[BI].Bl + bbase + cf * 1024);               \
    __builtin_amdgcn_s_setprio(1);                                             \
    _Pragma("unroll")                                                          \
    for (int rf = 0; rf < 8; rf++)                                             \
      _Pragma("unroll")                                                        \
      for (int cf = 0; cf < 4; cf++)                                           \
        acc[rf][cf] = __builtin_amdgcn_mfma_f32_16x16x32_bf16(fa[rf], fc[cf], acc[rf][cf], 0, 0, 0); \
    __builtin_amdgcn_s_setprio(0);                                             \
    _Pragma("unroll")                                                          \
    for (int rf = 0; rf < 8; rf++)                                             \
      fa[rf] = *(const bf16x8*)(lds[BI].Al + abase + rf * 1024);               \
    __builtin_amdgcn_s_setprio(1);                                             \
    _Pragma("unroll")                                                          \
    for (int rf = 0; rf < 8; rf++)                                             \
      _Pragma("unroll")                                                        \
      for (int cf = 0; cf < 4; cf++)                                           \
        acc[rf][cf] = __builtin_amdgcn_mfma_f32_16x16x32_bf16(fa[rf], fb[cf], acc[rf][cf], 0, 0, 0); \
    __builtin_amdgcn_s_setprio(0);                                             \
  } while (0)

// B0 seals prior-chunk reads of the buffer STAGE is about to overwrite; the
// counted vmcnt(8) waits only for the chunk-old stage (new loads span B1).
#define CHUNK(c_, BI, DOSTAGE) do {                                            \
    __builtin_amdgcn_sched_barrier(0);                                         \
    __builtin_amdgcn_s_barrier();                                              \
    if (DOSTAGE) { STAGE_K((c_) + 1, (BI) ^ 1);                                \
                   asm volatile("s_waitcnt vmcnt(8)" ::: "memory"); }          \
    else         { asm volatile("s_waitcnt vmcnt(0)" ::: "memory"); }          \
    __builtin_amdgcn_s_barrier();                                              \
    __builtin_amdgcn_sched_barrier(0);                                         \
    COMPUTE_K(BI);                                                             \
  } while (0)

#define EPILOGUE(T) do {                                                       \
    const float eqA = esq_s[(T) * 256 + wcol * 64 + lrow];                     \
    const float eqB = esq_s[(T) * 256 + wcol * 64 + 16 + lrow];                \
    const float eqC = esq_s[(T) * 256 + wcol * 64 + 32 + lrow];                \
    const float eqD = esq_s[(T) * 256 + wcol * 64 + 48 + lrow];                \
    const int code0 = ct * 512 + (T) * 256 + wcol * 64 + lrow;                 \
    _Pragma("unroll")                                                          \
    for (int rf = 0; rf < 8; rf++)                                             \
      _Pragma("unroll")                                                        \
      for (int reg = 0; reg < 4; reg++) {                                      \
        float v0 = fmaf(-2.f, acc[rf][0][reg], eqA);                           \
        float v1 = fmaf(-2.f, acc[rf][1][reg], eqB);                           \
        float v2 = fmaf(-2.f, acc[rf][2][reg], eqC);                           \
        float v3 = fmaf(-2.f, acc[rf][3][reg], eqD);                           \
        float a1 = v0, a2 = v1; int ka1 = code0, ka2 = code0 + 16;             \
        if (v1 < v0) { a1 = v1; ka1 = code0 + 16; a2 = v0; ka2 = code0; }      \
        float b1 = v2, b2 = v3; int kb1 = code0 + 32, kb2 = code0 + 48;        \
        if (v3 < v2) { b1 = v3; kb1 = code0 + 48; b2 = v2; kb2 = code0 + 32; } \
        float m1, m2; int k1, k2;                                              \
        if (a1 <= b1) { m1 = a1; k1 = ka1;                                     \
          if (b1 < a2) { m2 = b1; k2 = kb1; } else { m2 = a2; k2 = ka2; } }    \
        else { m1 = b1; k1 = kb1;                                              \
          if (a1 <= b2) { m2 = a1; k2 = ka1; } else { m2 = b2; k2 = kb2; } }   \
        _Pragma("unroll")                                                      \
        for (int mm = 1; mm <= 8; mm <<= 1) {                                  \
          float o1 = __shfl_xor(m1, mm); int j1 = __shfl_xor(k1, mm);          \
          float o2 = __shfl_xor(m2, mm); int j2 = __shfl_xor(k2, mm);          \
          bool t1 = (o1 < m1) || (o1 == m1 && j1 < k1);                        \
          bool t2 = (o1 < m2) || (o1 == m2 && j1 < k2);                        \
          float ns2 = t1 ? m1 : (t2 ? o1 : m2);                                \
          int   nc2 = t1 ? k1 : (t2 ? j1 : k2);                                \
          m1 = t1 ? o1 : m1; k1 = t1 ? j1 : k1; m2 = ns2; k2 = nc2;            \
          bool u1 = (o2 < m1) || (o2 == m1 && j2 < k1);                        \
          bool u2 = (o2 < m2) || (o2 == m2 && j2 < k2);                        \
          ns2 = u1 ? m1 : (u2 ? o2 : m2);                                      \
          nc2 = u1 ? k1 : (u2 ? j2 : k2);                                      \
          m1 = u1 ? o2 : m1; k1 = u1 ? j2 : k1; m2 = ns2; k2 = nc2;            \
        }                                                                      \
        if (lrow == 0) {                                                       \
          const int row = wrow * 128 + rf * 16 + lgrp * 4 + reg;               \
          if ((T) == 0) {                                                      \
            float4 p; p.x = m1; p.y = __int_as_float(k1);                      \
            p.z = m2; p.w = __int_as_float(k2);                                \
            mrg[row][wcol] = p;                                                \
          } else {                                                             \
            float4 p = mrg[row][wcol];                                         \
            float D1 = p.x; int C1 = __float_as_int(p.y);                      \
            float D2 = p.z; int C2 = __float_as_int(p.w);                      \
            if (m1 < D1 || (m1 == D1 && k1 < C1)) { D2 = D1; C2 = C1; D1 = m1; C1 = k1; } \
            else if (m1 < D2 || (m1 == D2 && k1 < C2)) { D2 = m1; C2 = k1; }   \
            if (m2 < D1 || (m2 == D1 && k2 < C1)) { D2 = D1; C2 = C1; D1 = m2; C1 = k2; } \
            else if (m2 < D2 || (m2 == D2 && k2 < C2)) { D2 = m2; C2 = k2; }   \
            p.x = D1; p.y = __int_as_float(C1);                                \
            p.z = D2; p.w = __int_as_float(C2);                                \
            mrg[row][wcol] = p;                                                \
          }                                                                    \
        }                                                                      \
      }                                                                        \
    if ((T) == 0) {                                                            \
      _Pragma("unroll")                                                        \
      for (int i = 0; i < 8; i++)                                              \
        _Pragma("unroll")                                                      \
        for (int j = 0; j < 4; j++) acc[i][j] = (f32x4){0.f, 0.f, 0.f, 0.f};   \
    }                                                                          \
  } while (0)

  f32x4 acc[8][4];
#pragma unroll
  for (int i = 0; i < 8; i++)
#pragma unroll
    for (int j = 0; j < 4; j++) acc[i][j] = (f32x4){0.f, 0.f, 0.f, 0.f};

  // prologue: esq for both tiles + chunk 0 into buf0; full drain once.
  esq_s[tid] = esqg[ct * 512 + tid];
  STAGE_K(0, 0);
  __syncthreads();

  for (int c2 = 0; c2 < 8; c2++) {
    const int c0 = c2 * 2;
    CHUNK(c0, 0, 1);
    if (c2 < 7) CHUNK(c0 + 1, 1, 1);
    else        CHUNK(15, 1, 0);
    if (c2 == 3) EPILOGUE(0);   // tile 0 done (chunks 0-7)
  }
  EPILOGUE(1);                  // tile 1 done; RMW-merged into mrg

#undef STAGE_K
#undef COMPUTE_K
#undef CHUNK
#undef EPILOGUE

  __syncthreads();  // mrg visible to all
  if (tid < 256) {
    float4 q = mrg[tid][0];
    float D1 = q.x; int C1 = __float_as_int(q.y);
    float D2 = q.z; int C2 = __float_as_int(q.w);
#pragma unroll
    for (int w = 1; w < 4; w++) {
      float4 p = mrg[tid][w];
      float a = p.x; int ka = __float_as_int(p.y);
      float b = p.z; int kb = __float_as_int(p.w);
      if (a < D1 || (a == D1 && ka < C1)) { D2 = D1; C2 = C1; D1 = a; C1 = ka; }
      else if (a < D2 || (a == D2 && ka < C2)) { D2 = a; C2 = ka; }
      if (b < D1 || (b == D1 && kb < C1)) { D2 = D1; C2 = C1; D1 = b; C1 = kb; }
      else if (b < D2 || (b == D2 && kb < C2)) { D2 = b; C2 = kb; }
    }
    float4 p;
    p.x = D1; p.y = __int_as_float(C1); p.z = D2; p.w = __int_as_float(C2);
    partials[(size_t)ct * N_TOT + rb * 256 + tid] = p;
  }
}

// ---------------- merge 16 slice partials + fp64 rescore ----------------
__global__ __launch_bounds__(128) void merge_rescore(
    const float* __restrict__ Z, const float* __restrict__ E,
    const float4* __restrict__ partials, float* __restrict__ out_idx_f) {
  const int row = blockIdx.x * 128 + threadIdx.x;
  float D1 = 3.4e38f, D2 = 3.4e38f; int C1 = 0, C2 = 0;
  for (int s = 0; s < 16; s++) {
    float4 p = partials[(size_t)s * N_TOT + row];
    float a = p.x; int ka = __float_as_int(p.y);
    float b = p.z; int kb = __float_as_int(p.w);
    if (a < D1 || (a == D1 && ka < C1)) { D2 = D1; C2 = C1; D1 = a; C1 = ka; }
    else if (a < D2 || (a == D2 && ka < C2)) { D2 = a; C2 = ka; }
    if (b < D1 || (b == D1 && kb < C1)) { D2 = D1; C2 = C1; D1 = b; C1 = kb; }
    else if (b < D2 || (b == D2 && kb < C2)) { D2 = b; C2 = kb; }
  }
  // fp64 rescore of top-2: resolves near-ties against the true distance
  const float* zp = Z + (size_t)row * D_DIM;
  const float* ep1 = E + (size_t)C1 * D_DIM;
  const float* ep2 = E + (size_t)C2 * D_DIM;
  double dd1 = 0.0, dd2 = 0.0;
  for (int d = 0; d < D_DIM; d += 4) {
    const float4 zv = *(const float4*)(zp + d);
    const float4 e1v = *(const float4*)(ep1 + d);
    const float4 e2v = *(const float4*)(ep2 + d);
    double t;
    t = (double)zv.x - (double)e1v.x; dd1 += t * t;
    t = (double)zv.y - (double)e1v.y; dd1 += t * t;
    t = (double)zv.z - (double)e1v.z; dd1 += t * t;
    t = (double)zv.w - (double)e1v.w; dd1 += t * t;
    t = (double)zv.x - (double)e2v.x; dd2 += t * t;
    t = (double)zv.y - (double)e2v.y; dd2 += t * t;
    t = (double)zv.z - (double)e2v.z; dd2 += t * t;
    t = (double)zv.w - (double)e2v.w; dd2 += t * t;
  }
  int fin = C1;
  if (dd2 < dd1 || (dd2 == dd1 && C2 < C1)) fin = C2;
  out_idx_f[row] = (float)fin;
}

// ---------------- gather z_q, loss partial per block (no hot atomic) ----------------
__global__ __launch_bounds__(256) void gather_kernel(
    const float* __restrict__ Z, const float* __restrict__ E,
    const float* __restrict__ idx_f, float* __restrict__ zq_out,
    float* __restrict__ counts, float* __restrict__ loss_part) {
  const int t = threadIdx.x;
  float lsum = 0.0f;
  for (int rr = 0; rr < 16; rr++) {
    const int row = blockIdx.x * 16 + rr;
    const int c = (int)idx_f[row];
    const float e = E[(size_t)c * D_DIM + t];
    const float z = Z[(size_t)row * D_DIM + t];
    zq_out[(size_t)row * D_DIM + t] = e;
    const float d = z - e;
    lsum += d * d;
    if (t == 0) atomicAdd(&counts[c], 1.0f);  // 8192 addresses, low contention
  }
#pragma unroll
  for (int off = 32; off > 0; off >>= 1) lsum += __shfl_down(lsum, off);
  __shared__ float wsum[4];
  if ((t & 63) == 0) wsum[t >> 6] = lsum;
  __syncthreads();
  if (t == 0) loss_part[blockIdx.x] = wsum[0] + wsum[1] + wsum[2] + wsum[3];
}

// ---------------- loss scale + perplexity ----------------
__global__ __launch_bounds__(256) void final_kernel(
    const float* __restrict__ counts, const float* __restrict__ loss_part,
    float* __restrict__ out) {
  const int t = threadIdx.x;
  float h = 0.0f, ls = 0.0f;
  for (int k = t; k < K_CB; k += 256) {
    const float p = counts[k] * (1.0f / (float)N_TOT);
    h += p * logf(p + 1e-12f);
  }
  for (int k = t; k < 2048; k += 256) ls += loss_part[k];
#pragma unroll
  for (int off = 32; off > 0; off >>= 1) {
    h += __shfl_down(h, off);
    ls += __shfl_down(ls, off);
  }
  __shared__ float ws4[4], ls4[4];
  if ((t & 63) == 0) { ws4[t >> 6] = h; ls4[t >> 6] = ls; }
  __syncthreads();
  if (t == 0) {
    const float H = ws4[0] + ws4[1] + ws4[2] + ws4[3];
    const float L = ls4[0] + ls4[1] + ls4[2] + ls4[3];
    out[OUT_LOSS] = 1.25f * L * (1.0f / (float)(N_TOT * D_DIM));
    out[OUT_PERP] = expf(-H);
  }
}

extern "C" void kernel_launch(void* const* d_in, const int* in_sizes, int n_in,
                              void* d_out, int out_size, void* d_ws, size_t ws_size,
                              hipStream_t stream) {
  (void)in_sizes; (void)n_in; (void)out_size; (void)ws_size;
  const float* Z = (const float*)d_in[0];
  const float* E = (const float*)d_in[1];
  float* out = (float*)d_out;
  char* ws = (char*)d_ws;
  char* Aimg = ws + WS_AIMG;
  char* Bimg = ws + WS_BIMG;
  float4* partials = (float4*)(ws + WS_PART);
  float* esqg = (float*)(ws + WS_ESQ);
  float* counts = (float*)(ws + WS_COUNTS);
  float* loss_part = (float*)(ws + WS_LPART);

  hipMemsetAsync(ws + WS_COUNTS, 0, 32768, stream);  // counts only
  prep_z<<<dim3(4096), dim3(256), 0, stream>>>(Z, Aimg);
  prep_e<<<dim3(1024), dim3(256), 0, stream>>>(E, Bimg, esqg);
  argmin_mfma<<<dim3(2048), dim3(512), 0, stream>>>(Aimg, Bimg, esqg, partials);
  merge_rescore<<<dim3(256), dim3(128), 0, stream>>>(Z, E, partials, out + OUT_IDX);
  gather_kernel<<<dim3(2048), dim3(256), 0, stream>>>(Z, E, out + OUT_IDX, out, counts, loss_part);
  final_kernel<<<dim3(1), dim3(256), 0, stream>>>(counts, loss_part, out);
}

// Round 7
// 665.331 us; speedup vs baseline: 2.8195x; 2.8195x over previous
//
#include <hip/hip_runtime.h>
#include <math.h>

#define N_TOT 32768
#define K_CB 8192
#define D_DIM 256

#define OUT_IDX  (N_TOT * D_DIM)   // 8388608
#define OUT_LOSS (OUT_IDX + N_TOT) // 8421376
#define OUT_PERP (OUT_LOSS + 1)

// ---- workspace layout (bytes), total 50,405,376 (proven budget) ----
#define WS_AIMG   0u
#define AIMG_SZ   (256u * 16u * 8192u)           // 33,554,432
#define WS_BIMG   (WS_AIMG + AIMG_SZ)
#define BIMG_SZ   (64u * 16u * 8192u)            // 8,388,608
#define WS_PART   (WS_BIMG + BIMG_SZ)            // 16 slices x 32768 x float4
#define PART_SZ   (16u * 32768u * 16u)           // 8,388,608
#define WS_ESQ    (WS_PART + PART_SZ)            // 8192 f32
#define WS_COUNTS (WS_ESQ + 32768u)              // 8192 f32
#define WS_LPART  (WS_COUNTS + 32768u)           // 2048 f32 loss partials

typedef short bf16x8 __attribute__((ext_vector_type(8)));
typedef float f32x4  __attribute__((ext_vector_type(4)));
typedef unsigned short u16x8 __attribute__((ext_vector_type(8)));

__device__ __forceinline__ unsigned short f2bf(float x) {  // RNE f32 -> bf16
  unsigned int b = __float_as_uint(x);
  b = b + 0x7FFFu + ((b >> 16) & 1u);
  return (unsigned short)(b >> 16);
}
__device__ __forceinline__ float bf2f(unsigned short h) {
  return __uint_as_float(((unsigned int)h) << 16);
}
__device__ __forceinline__ void gld16(const void* g, void* l) {
  __builtin_amdgcn_global_load_lds(
      (const __attribute__((address_space(1))) void*)g,
      (__attribute__((address_space(3))) void*)l, 16, 0, 0);
}

// ---------------- prep: Z -> packed swizzled bf16 hi/lo tile image ----------------
// Chunk c of row r stored at slot c ^ ((r>>1)&3): linear global_load_lds lands it
// pre-swizzled; the frag ds_read applies the same XOR (both-sides rule).
__global__ __launch_bounds__(256) void prep_z(const float* __restrict__ Z,
                                              char* __restrict__ Aimg) {
  const int tid = threadIdx.x;
  const int row = blockIdx.x * 8 + (tid >> 5);
  const int ch = tid & 31;           // kt = ch>>2, chunk c = ch&3
  const int kt = ch >> 2, c = ch & 3;
  const int rb = row >> 7, r = row & 127;
  const float4 z0 = *(const float4*)(Z + (size_t)row * D_DIM + kt * 32 + c * 8);
  const float4 z1 = *(const float4*)(Z + (size_t)row * D_DIM + kt * 32 + c * 8 + 4);
  u16x8 h, l;
  h[0] = f2bf(z0.x); l[0] = f2bf(z0.x - bf2f(h[0]));
  h[1] = f2bf(z0.y); l[1] = f2bf(z0.y - bf2f(h[1]));
  h[2] = f2bf(z0.z); l[2] = f2bf(z0.z - bf2f(h[2]));
  h[3] = f2bf(z0.w); l[3] = f2bf(z0.w - bf2f(h[3]));
  h[4] = f2bf(z1.x); l[4] = f2bf(z1.x - bf2f(h[4]));
  h[5] = f2bf(z1.y); l[5] = f2bf(z1.y - bf2f(h[5]));
  h[6] = f2bf(z1.z); l[6] = f2bf(z1.z - bf2f(h[6]));
  h[7] = f2bf(z1.w); l[7] = f2bf(z1.w - bf2f(h[7]));
  const int cs = c ^ ((r >> 1) & 3);
  const size_t off = (size_t)r * 64 + cs * 16;
  *(u16x8*)(Aimg + (size_t)(rb * 16 + kt) * 8192 + off) = h;
  *(u16x8*)(Aimg + (size_t)(rb * 16 + 8 + kt) * 8192 + off) = l;
}

// ---------------- prep: E -> packed swizzled image + e_sq ----------------
__global__ __launch_bounds__(256) void prep_e(const float* __restrict__ E,
                                              char* __restrict__ Bimg,
                                              float* __restrict__ esqg) {
  const int tid = threadIdx.x;
  const int code = blockIdx.x * 8 + (tid >> 5);
  const int ch = tid & 31;
  const int kt = ch >> 2, c = ch & 3;
  const int ntg = code >> 7, r = code & 127;
  const float4 e0 = *(const float4*)(E + (size_t)code * D_DIM + kt * 32 + c * 8);
  const float4 e1 = *(const float4*)(E + (size_t)code * D_DIM + kt * 32 + c * 8 + 4);
  u16x8 h, l;
  h[0] = f2bf(e0.x); l[0] = f2bf(e0.x - bf2f(h[0]));
  h[1] = f2bf(e0.y); l[1] = f2bf(e0.y - bf2f(h[1]));
  h[2] = f2bf(e0.z); l[2] = f2bf(e0.z - bf2f(h[2]));
  h[3] = f2bf(e0.w); l[3] = f2bf(e0.w - bf2f(h[3]));
  h[4] = f2bf(e1.x); l[4] = f2bf(e1.x - bf2f(h[4]));
  h[5] = f2bf(e1.y); l[5] = f2bf(e1.y - bf2f(h[5]));
  h[6] = f2bf(e1.z); l[6] = f2bf(e1.z - bf2f(h[6]));
  h[7] = f2bf(e1.w); l[7] = f2bf(e1.w - bf2f(h[7]));
  const int cs = c ^ ((r >> 1) & 3);
  const size_t off = (size_t)r * 64 + cs * 16;
  *(u16x8*)(Bimg + (size_t)(ntg * 16 + kt) * 8192 + off) = h;
  *(u16x8*)(Bimg + (size_t)(ntg * 16 + 8 + kt) * 8192 + off) = l;
  float s = e0.x * e0.x + e0.y * e0.y + e0.z * e0.z + e0.w * e0.w +
            e1.x * e1.x + e1.y * e1.y + e1.z * e1.z + e1.w * e1.w;
#pragma unroll
  for (int o = 16; o > 0; o >>= 1) s += __shfl_down(s, o, 32);
  if ((tid & 31) == 0) esqg[code] = s;
}

// ---------------- MFMA distance GEMM + fused top-2 argmin ----------------
// bid = rb*16 + ntp*8 + cb; block covers 128 rows x 4 code tiles (32 chunks).
// Counted-vmcnt double-buffer: per chunk {sched_barrier; s_barrier; STAGE(c+1
// -> buf^1); vmcnt(8) [waits only the chunk-old stage; new loads stay in
// flight across barriers]; s_barrier; sched_barrier; COMPUTE}. Fully unrolled
// so stage addresses are compile-time. 3 products (zh*eh + zh*el + zl*eh).
__global__ __launch_bounds__(256, 2) void argmin_mfma(
    const char* __restrict__ Aimg, const char* __restrict__ Bimg,
    const float* __restrict__ esqg, float4* __restrict__ partials) {
  __shared__ __align__(16) union {
    struct { char Ah[8192]; char Al[8192]; char Bh[8192]; char Bl[8192]; } t[2];  // 64 KB
    float4 mbuf[128][2];                                                          // 4 KB
  } u;
  __shared__ float esq_s[512];  // all 4 tiles' e_sq

  const int tid = threadIdx.x;
  const int lane = tid & 63;
  const int wid = tid >> 6;
  const int wrow = wid >> 1, wcol = wid & 1;
  const int lrow = lane & 15, lgrp = lane >> 4;
  const int cb = blockIdx.x & 7;
  const int ntp = (blockIdx.x >> 3) & 1;
  const int rb = blockIdx.x >> 4;
  const int ntg0 = cb * 8 + ntp * 4;

  // frag read: row R's logical chunk lgrp lives at slot lgrp ^ ((R>>1)&3);
  // R = w*64 + rf*16 + lrow -> XOR term depends only on lrow.
  const int sw = (lrow >> 1) & 3;
  const int aoff = (wrow * 64 + lrow) * 64 + (lgrp ^ sw) * 16;
  const int boff = (wcol * 64 + lrow) * 64 + (lgrp ^ sw) * 16;
  const char* Abase = Aimg + (size_t)rb * (16u * 8192u);
  const char* Bbase0 = Bimg + (size_t)ntg0 * (16u * 8192u);
  const int soff = tid * 16;

  float s1[16], s2[16]; int c1[16], c2[16];
#pragma unroll
  for (int i = 0; i < 16; i++) { s1[i] = 3.4e38f; s2[i] = 3.4e38f; c1[i] = 0; c2[i] = 0; }

#define STAGE_K(kk, BI) do {                                                   \
    const int k_ = (kk) & 7, nti_ = (kk) >> 3;                                 \
    const char* ah_ = Abase + (size_t)k_ * 8192;                               \
    const char* al_ = Abase + (size_t)(8 + k_) * 8192;                         \
    const char* bb_ = Bbase0 + (size_t)nti_ * (16u * 8192u);                   \
    const char* bh_ = bb_ + (size_t)k_ * 8192;                                 \
    const char* bl_ = bb_ + (size_t)(8 + k_) * 8192;                           \
    gld16(ah_ + soff,        u.t[BI].Ah + soff);                               \
    gld16(ah_ + 4096 + soff, u.t[BI].Ah + 4096 + soff);                        \
    gld16(al_ + soff,        u.t[BI].Al + soff);                               \
    gld16(al_ + 4096 + soff, u.t[BI].Al + 4096 + soff);                        \
    gld16(bh_ + soff,        u.t[BI].Bh + soff);                               \
    gld16(bh_ + 4096 + soff, u.t[BI].Bh + 4096 + soff);                        \
    gld16(bl_ + soff,        u.t[BI].Bl + soff);                               \
    gld16(bl_ + 4096 + soff, u.t[BI].Bl + 4096 + soff);                        \
  } while (0)

#define COMPUTE_K(BI) do {                                                     \
    bf16x8 afh[4], afl[4], bfh[4], bfl[4];                                     \
    _Pragma("unroll")                                                          \
    for (int rf = 0; rf < 4; rf++) {                                           \
      afh[rf] = *(const bf16x8*)(u.t[BI].Ah + aoff + rf * 1024);               \
      afl[rf] = *(const bf16x8*)(u.t[BI].Al + aoff + rf * 1024);               \
    }                                                                          \
    _Pragma("unroll")                                                          \
    for (int cf = 0; cf < 4; cf++) {                                           \
      bfh[cf] = *(const bf16x8*)(u.t[BI].Bh + boff + cf * 1024);               \
      bfl[cf] = *(const bf16x8*)(u.t[BI].Bl + boff + cf * 1024);               \
    }                                                                          \
    __builtin_amdgcn_s_setprio(1);                                             \
    _Pragma("unroll")                                                          \
    for (int rf = 0; rf < 4; rf++)                                             \
      _Pragma("unroll")                                                        \
      for (int cf = 0; cf < 4; cf++)                                           \
        acc[rf][cf] = __builtin_amdgcn_mfma_f32_16x16x32_bf16(afh[rf], bfh[cf], acc[rf][cf], 0, 0, 0); \
    __builtin_amdgcn_s_setprio(0);                                             \
    __builtin_amdgcn_s_setprio(1);                                             \
    _Pragma("unroll")                                                          \
    for (int rf = 0; rf < 4; rf++)                                             \
      _Pragma("unroll")                                                        \
      for (int cf = 0; cf < 4; cf++)                                           \
        acc[rf][cf] = __builtin_amdgcn_mfma_f32_16x16x32_bf16(afh[rf], bfl[cf], acc[rf][cf], 0, 0, 0); \
    __builtin_amdgcn_s_setprio(0);                                             \
    __builtin_amdgcn_s_setprio(1);                                             \
    _Pragma("unroll")                                                          \
    for (int rf = 0; rf < 4; rf++)                                             \
      _Pragma("unroll")                                                        \
      for (int cf = 0; cf < 4; cf++)                                           \
        acc[rf][cf] = __builtin_amdgcn_mfma_f32_16x16x32_bf16(afl[rf], bfh[cf], acc[rf][cf], 0, 0, 0); \
    __builtin_amdgcn_s_setprio(0);                                             \
  } while (0)

#define EPILOGUE(T) do {                                                       \
    const int code0 = (ntg0 + (T)) * 128 + wcol * 64 + lrow;                   \
    float eq0 = esq_s[(T) * 128 + wcol * 64 + lrow];                           \
    float eq1 = esq_s[(T) * 128 + wcol * 64 + 16 + lrow];                      \
    float eq2 = esq_s[(T) * 128 + wcol * 64 + 32 + lrow];                      \
    float eq3 = esq_s[(T) * 128 + wcol * 64 + 48 + lrow];                      \
    _Pragma("unroll")                                                          \
    for (int rf = 0; rf < 4; rf++)                                             \
      _Pragma("unroll")                                                        \
      for (int reg = 0; reg < 4; reg++) {                                      \
        const int r = rf * 4 + reg;                                            \
        float v0 = fmaf(-2.f, acc[rf][0][reg], eq0);                           \
        float v1 = fmaf(-2.f, acc[rf][1][reg], eq1);                           \
        float v2 = fmaf(-2.f, acc[rf][2][reg], eq2);                           \
        float v3 = fmaf(-2.f, acc[rf][3][reg], eq3);                           \
        float a1 = v0, a2 = v1; int ka1 = code0, ka2 = code0 + 16;             \
        if (v1 < v0) { a1 = v1; ka1 = code0 + 16; a2 = v0; ka2 = code0; }      \
        float b1v = v2, b2v = v3; int kb1 = code0 + 32, kb2 = code0 + 48;      \
        if (v3 < v2) { b1v = v3; kb1 = code0 + 48; b2v = v2; kb2 = code0 + 32; } \
        float m1, m2; int k1, k2;                                              \
        if (a1 <= b1v) { m1 = a1; k1 = ka1;                                    \
          if (b1v < a2) { m2 = b1v; k2 = kb1; } else { m2 = a2; k2 = ka2; } }  \
        else { m1 = b1v; k1 = kb1;                                             \
          if (a1 <= b2v) { m2 = a1; k2 = ka1; } else { m2 = b2v; k2 = kb2; } } \
        if (m1 < s1[r]) {                                                      \
          s2[r] = (m2 < s1[r]) ? m2 : s1[r];                                   \
          c2[r] = (m2 < s1[r]) ? k2 : c1[r];                                   \
          s1[r] = m1; c1[r] = k1;                                              \
        } else if (m1 < s2[r]) {                                               \
          s2[r] = m1; c2[r] = k1;                                              \
        }                                                                      \
      }                                                                        \
    _Pragma("unroll")                                                          \
    for (int i = 0; i < 4; i++)                                                \
      _Pragma("unroll")                                                        \
      for (int j = 0; j < 4; j++) acc[i][j] = (f32x4){0.f, 0.f, 0.f, 0.f};     \
  } while (0)

  // prologue: esq for all 4 tiles + chunk 0 into buf0; one full drain.
  esq_s[tid] = esqg[ntg0 * 128 + tid];
  esq_s[tid + 256] = esqg[ntg0 * 128 + tid + 256];
  STAGE_K(0, 0);

  f32x4 acc[4][4];
#pragma unroll
  for (int i = 0; i < 4; i++)
#pragma unroll
    for (int j = 0; j < 4; j++) acc[i][j] = (f32x4){0.f, 0.f, 0.f, 0.f};

  __syncthreads();  // drains vmcnt(0): buf0 + esq_s ready

#pragma unroll
  for (int c = 0; c < 32; c++) {
    const int bi = c & 1;
    __builtin_amdgcn_sched_barrier(0);
    __builtin_amdgcn_s_barrier();            // prev chunk's reads of buf[bi^1] done
    if (c < 31) {
      STAGE_K(c + 1, bi ^ 1);                // 8 loads issued; stay in flight
      asm volatile("s_waitcnt vmcnt(8)" ::: "memory");  // chunk-old stage landed
    } else {
      asm volatile("s_waitcnt vmcnt(0)" ::: "memory");
    }
    __builtin_amdgcn_s_barrier();            // buf[bi] complete for all waves
    __builtin_amdgcn_sched_barrier(0);
    COMPUTE_K(bi);
    if ((c & 7) == 7) EPILOGUE(c >> 3);
  }
#undef STAGE_K
#undef COMPUTE_K
#undef EPILOGUE

  // shuffle-butterfly merge across the 16 lrow lanes (disjoint code columns;
  // lexicographic (val, idx) compare keeps lowest-index-wins on ties)
#pragma unroll
  for (int r = 0; r < 16; r++) {
#pragma unroll
    for (int m = 1; m <= 8; m <<= 1) {
      float o1 = __shfl_xor(s1[r], m); int k1 = __shfl_xor(c1[r], m);
      float o2 = __shfl_xor(s2[r], m); int k2 = __shfl_xor(c2[r], m);
      bool t1 = (o1 < s1[r]) || (o1 == s1[r] && k1 < c1[r]);
      bool t2 = (o1 < s2[r]) || (o1 == s2[r] && k1 < c2[r]);
      float ns2 = t1 ? s1[r] : (t2 ? o1 : s2[r]);
      int   nc2 = t1 ? c1[r] : (t2 ? k1 : c2[r]);
      s1[r] = t1 ? o1 : s1[r]; c1[r] = t1 ? k1 : c1[r];
      s2[r] = ns2; c2[r] = nc2;
      bool u1 = (o2 < s1[r]) || (o2 == s1[r] && k2 < c1[r]);
      bool u2 = (o2 < s2[r]) || (o2 == s2[r] && k2 < c2[r]);
      ns2 = u1 ? s1[r] : (u2 ? o2 : s2[r]);
      nc2 = u1 ? c1[r] : (u2 ? k2 : c2[r]);
      s1[r] = u1 ? o2 : s1[r]; c1[r] = u1 ? k2 : c1[r];
      s2[r] = ns2; c2[r] = nc2;
    }
  }

  __syncthreads();  // all tile reads + in-flight stages done; reuse union
  if (lrow == 0) {
#pragma unroll
    for (int rf = 0; rf < 4; rf++)
#pragma unroll
      for (int reg = 0; reg < 4; reg++) {
        const int r = rf * 4 + reg;
        const int row = wrow * 64 + rf * 16 + lgrp * 4 + reg;
        float4 p;
        p.x = s1[r]; p.y = __int_as_float(c1[r]);
        p.z = s2[r]; p.w = __int_as_float(c2[r]);
        u.mbuf[row][wcol] = p;
      }
  }
  __syncthreads();
  if (tid < 128) {
    float4 pa = u.mbuf[tid][0];
    float4 pb = u.mbuf[tid][1];
    float D1 = pa.x; int C1 = __float_as_int(pa.y);
    float D2 = pa.z; int C2 = __float_as_int(pa.w);
    float a = pb.x; int ka = __float_as_int(pb.y);
    float b = pb.z; int kb = __float_as_int(pb.w);
    if (a < D1 || (a == D1 && ka < C1)) { D2 = D1; C2 = C1; D1 = a; C1 = ka; }
    else if (a < D2 || (a == D2 && ka < C2)) { D2 = a; C2 = ka; }
    if (b < D1 || (b == D1 && kb < C1)) { D2 = D1; C2 = C1; D1 = b; C1 = kb; }
    else if (b < D2 || (b == D2 && kb < C2)) { D2 = b; C2 = kb; }
    float4 p;
    p.x = D1; p.y = __int_as_float(C1); p.z = D2; p.w = __int_as_float(C2);
    partials[(size_t)(ntp * 8 + cb) * N_TOT + rb * 128 + tid] = p;
  }
}

// ---------------- merge 16 slice partials + fp64 rescore ----------------
__global__ __launch_bounds__(128) void merge_rescore(
    const float* __restrict__ Z, const float* __restrict__ E,
    const float4* __restrict__ partials, float* __restrict__ out_idx_f) {
  const int row = blockIdx.x * 128 + threadIdx.x;
  float D1 = 3.4e38f, D2 = 3.4e38f; int C1 = 0, C2 = 0;
  for (int s = 0; s < 16; s++) {
    float4 p = partials[(size_t)s * N_TOT + row];
    float a = p.x; int ka = __float_as_int(p.y);
    float b = p.z; int kb = __float_as_int(p.w);
    if (a < D1 || (a == D1 && ka < C1)) { D2 = D1; C2 = C1; D1 = a; C1 = ka; }
    else if (a < D2 || (a == D2 && ka < C2)) { D2 = a; C2 = ka; }
    if (b < D1 || (b == D1 && kb < C1)) { D2 = D1; C2 = C1; D1 = b; C1 = kb; }
    else if (b < D2 || (b == D2 && kb < C2)) { D2 = b; C2 = kb; }
  }
  // fp64 rescore of top-2: resolves near-ties against the true distance
  const float* zp = Z + (size_t)row * D_DIM;
  const float* ep1 = E + (size_t)C1 * D_DIM;
  const float* ep2 = E + (size_t)C2 * D_DIM;
  double dd1 = 0.0, dd2 = 0.0;
  for (int d = 0; d < D_DIM; d += 4) {
    const float4 zv = *(const float4*)(zp + d);
    const float4 e1v = *(const float4*)(ep1 + d);
    const float4 e2v = *(const float4*)(ep2 + d);
    double t;
    t = (double)zv.x - (double)e1v.x; dd1 += t * t;
    t = (double)zv.y - (double)e1v.y; dd1 += t * t;
    t = (double)zv.z - (double)e1v.z; dd1 += t * t;
    t = (double)zv.w - (double)e1v.w; dd1 += t * t;
    t = (double)zv.x - (double)e2v.x; dd2 += t * t;
    t = (double)zv.y - (double)e2v.y; dd2 += t * t;
    t = (double)zv.z - (double)e2v.z; dd2 += t * t;
    t = (double)zv.w - (double)e2v.w; dd2 += t * t;
  }
  int fin = C1;
  if (dd2 < dd1 || (dd2 == dd1 && C2 < C1)) fin = C2;
  out_idx_f[row] = (float)fin;
}

// ---------------- gather z_q, loss partial per block (no hot atomic) ----------------
__global__ __launch_bounds__(256) void gather_kernel(
    const float* __restrict__ Z, const float* __restrict__ E,
    const float* __restrict__ idx_f, float* __restrict__ zq_out,
    float* __restrict__ counts, float* __restrict__ loss_part) {
  const int t = threadIdx.x;
  float lsum = 0.0f;
  for (int rr = 0; rr < 16; rr++) {
    const int row = blockIdx.x * 16 + rr;
    const int c = (int)idx_f[row];
    const float e = E[(size_t)c * D_DIM + t];
    const float z = Z[(size_t)row * D_DIM + t];
    zq_out[(size_t)row * D_DIM + t] = e;
    const float d = z - e;
    lsum += d * d;
    if (t == 0) atomicAdd(&counts[c], 1.0f);  // 8192 addresses, low contention
  }
#pragma unroll
  for (int off = 32; off > 0; off >>= 1) lsum += __shfl_down(lsum, off);
  __shared__ float wsum[4];
  if ((t & 63) == 0) wsum[t >> 6] = lsum;
  __syncthreads();
  if (t == 0) loss_part[blockIdx.x] = wsum[0] + wsum[1] + wsum[2] + wsum[3];
}

// ---------------- loss scale + perplexity ----------------
__global__ __launch_bounds__(256) void final_kernel(
    const float* __restrict__ counts, const float* __restrict__ loss_part,
    float* __restrict__ out) {
  const int t = threadIdx.x;
  float h = 0.0f, ls = 0.0f;
  for (int k = t; k < K_CB; k += 256) {
    const float p = counts[k] * (1.0f / (float)N_TOT);
    h += p * logf(p + 1e-12f);
  }
  for (int k = t; k < 2048; k += 256) ls += loss_part[k];
#pragma unroll
  for (int off = 32; off > 0; off >>= 1) {
    h += __shfl_down(h, off);
    ls += __shfl_down(ls, off);
  }
  __shared__ float ws4[4], ls4[4];
  if ((t & 63) == 0) { ws4[t >> 6] = h; ls4[t >> 6] = ls; }
  __syncthreads();
  if (t == 0) {
    const float H = ws4[0] + ws4[1] + ws4[2] + ws4[3];
    const float L = ls4[0] + ls4[1] + ls4[2] + ls4[3];
    out[OUT_LOSS] = 1.25f * L * (1.0f / (float)(N_TOT * D_DIM));
    out[OUT_PERP] = expf(-H);
  }
}

extern "C" void kernel_launch(void* const* d_in, const int* in_sizes, int n_in,
                              void* d_out, int out_size, void* d_ws, size_t ws_size,
                              hipStream_t stream) {
  (void)in_sizes; (void)n_in; (void)out_size; (void)ws_size;
  const float* Z = (const float*)d_in[0];
  const float* E = (const float*)d_in[1];
  float* out = (float*)d_out;
  char* ws = (char*)d_ws;
  char* Aimg = ws + WS_AIMG;
  char* Bimg = ws + WS_BIMG;
  float4* partials = (float4*)(ws + WS_PART);
  float* esqg = (float*)(ws + WS_ESQ);
  float* counts = (float*)(ws + WS_COUNTS);
  float* loss_part = (float*)(ws + WS_LPART);

  hipMemsetAsync(ws + WS_COUNTS, 0, 32768, stream);  // counts only
  prep_z<<<dim3(4096), dim3(256), 0, stream>>>(Z, Aimg);
  prep_e<<<dim3(1024), dim3(256), 0, stream>>>(E, Bimg, esqg);
  argmin_mfma<<<dim3(4096), dim3(256), 0, stream>>>(Aimg, Bimg, esqg, partials);
  merge_rescore<<<dim3(256), dim3(128), 0, stream>>>(Z, E, partials, out + OUT_IDX);
  gather_kernel<<<dim3(2048), dim3(256), 0, stream>>>(Z, E, out + OUT_IDX, out, counts, loss_part);
  final_kernel<<<dim3(1), dim3(256), 0, stream>>>(counts, loss_part, out);
}